// Round 1
// baseline (1181.558 us; speedup 1.0000x reference)
//
#include <hip/hip_runtime.h>
#include <hip/hip_bf16.h>

#define DM     1024   // model dim
#define NSLOT  128    // experts*sets
#define TG     32     // tokens per group
#define NGROUP 256    // B * (SEQ/TG)
#define FF     32     // expert size
#define FHALF  16

// ---------------------------------------------------------------------------
// Kernel A: fused controller logits + tie-broken argmax.
// grid = 256 groups, 512 threads. Per block: 32x1024 @ 1024x128 fp32 GEMM,
// logits staged in LDS, then argmax over the 32 tokens per slot.
// ---------------------------------------------------------------------------
__global__ __launch_bounds__(512) void ka_logits_argmax(
    const float* __restrict__ x, const float* __restrict__ ctrl,
    int* __restrict__ idx)
{
    __shared__ float Lg[TG][NSLOT];   // 16 KB
    const int bg = blockIdx.x;
    const int n  = threadIdx.x & 127;   // slot
    const int mh = threadIdx.x >> 7;    // 0..3 -> rows mh*8 .. mh*8+7
    const float* xp = x + (size_t)(bg * TG + mh * 8) * DM;
    const float* cp = ctrl + n;

    float acc[8];
#pragma unroll
    for (int m = 0; m < 8; ++m) acc[m] = 0.0f;

    for (int k = 0; k < DM; k += 4) {
        const float c0 = cp[(k + 0) * NSLOT];
        const float c1 = cp[(k + 1) * NSLOT];
        const float c2 = cp[(k + 2) * NSLOT];
        const float c3 = cp[(k + 3) * NSLOT];
#pragma unroll
        for (int m = 0; m < 8; ++m) {
            const float4 xv = *reinterpret_cast<const float4*>(xp + m * DM + k);
            float a = acc[m];
            a = fmaf(xv.x, c0, a);
            a = fmaf(xv.y, c1, a);
            a = fmaf(xv.z, c2, a);
            a = fmaf(xv.w, c3, a);
            acc[m] = a;
        }
    }
#pragma unroll
    for (int m = 0; m < 8; ++m) Lg[mh * 8 + m][n] = acc[m];
    __syncthreads();

    if (threadIdx.x < NSLOT) {
        const int es = threadIdx.x;
        float best = -1e30f;
        int bi = 0;
#pragma unroll
        for (int t = 0; t < TG; ++t) {
            // same tiebreak as reference: + linspace(0,1e-6,32)[t]
            const float v = Lg[t][es] + (float)t * (1e-6f / 31.0f);
            if (v >= best) { best = v; bi = t; }   // later token wins ties
        }
        idx[bg * NSLOT + es] = bi;
    }
}

// ---------------------------------------------------------------------------
// Kernel B: per-slot FFN + atomic scatter-add.
// grid = 128 slots * 2 f-halves = 256 blocks, 1024 threads, 131 KB dyn LDS.
// LDS: F1T[16][1028] (f1 half, transposed, padded) + F2h[16][1024].
// Each wave handles 16 groups, register-blocked 4 at a time.
// ---------------------------------------------------------------------------
__global__ __launch_bounds__(1024, 4) void kb_ffn_scatter(
    const float* __restrict__ x, const float* __restrict__ f1,
    const float* __restrict__ bias, const float* __restrict__ f2,
    const int* __restrict__ idx, float* __restrict__ out)
{
    extern __shared__ float smem[];
    float* F1T = smem;                 // [16][1028]
    float* F2h = smem + FHALF * 1028;  // [16][1024]

    const int es = blockIdx.x >> 1;
    const int fh = blockIdx.x & 1;

    // stage f1 half: f1[d, es, f] flat = d*4096 + es*32 + f
    for (int i = threadIdx.x; i < FHALF * DM; i += 1024) {
        const int d = i >> 4, j = i & 15;
        F1T[j * 1028 + d] = f1[(size_t)d * 4096 + es * FF + fh * FHALF + j];
    }
    // stage f2 half: f2[es, f, d] flat = es*32768 + f*1024 + d
    for (int i = threadIdx.x; i < FHALF * DM; i += 1024) {
        const int j = i >> 10, d = i & 1023;
        F2h[j * DM + d] = f2[(size_t)es * (FF * DM) + (fh * FHALF + j) * DM + d];
    }
    __syncthreads();

    const int wave = threadIdx.x >> 6;
    const int lane = threadIdx.x & 63;
    const int j = lane & 15;       // which f output within the half
    const int c = lane >> 4;       // d-chunk 0..3 (256 each)
    const float b = bias[es * FF + fh * FHALF + j];

    for (int k4 = 0; k4 < 4; ++k4) {
        int gs[4], tok[4];
        const float* xr[4];
#pragma unroll
        for (int i = 0; i < 4; ++i) {
            gs[i]  = wave + 16 * (k4 * 4 + i);
            tok[i] = idx[gs[i] * NSLOT + es];
            xr[i]  = x + (size_t)(gs[i] * TG + tok[i]) * DM;
        }

        // stage A: h[j] = sum_d x[d] * f1T[j][d]  (this lane: d in [c*256, c*256+256))
        float h[4] = {0.0f, 0.0f, 0.0f, 0.0f};
        const int d0 = c * 256;
#pragma unroll 2
        for (int s = 0; s < 64; ++s) {
            const int d = d0 + 4 * s;
            const float4 w = *reinterpret_cast<const float4*>(&F1T[j * 1028 + d]);
#pragma unroll
            for (int i = 0; i < 4; ++i) {
                const float4 xv = *reinterpret_cast<const float4*>(xr[i] + d);
                h[i] = fmaf(xv.x, w.x, h[i]);
                h[i] = fmaf(xv.y, w.y, h[i]);
                h[i] = fmaf(xv.z, w.z, h[i]);
                h[i] = fmaf(xv.w, w.w, h[i]);
            }
        }
        // reduce over the 4 d-chunks, bias + relu
#pragma unroll
        for (int i = 0; i < 4; ++i) {
            h[i] += __shfl_xor(h[i], 16);
            h[i] += __shfl_xor(h[i], 32);
            h[i] = fmaxf(h[i] + b, 0.0f);
        }

        // stage B: y[d] = sum_j h[j] * f2h[j][d]; lane handles d = 64*kk + lane
        float y[4][16];
#pragma unroll
        for (int i = 0; i < 4; ++i)
#pragma unroll
            for (int kk = 0; kk < 16; ++kk) y[i][kk] = 0.0f;

#pragma unroll
        for (int jp = 0; jp < 16; ++jp) {
            const float h0 = __shfl(h[0], jp);
            const float h1 = __shfl(h[1], jp);
            const float h2 = __shfl(h[2], jp);
            const float h3 = __shfl(h[3], jp);
#pragma unroll
            for (int kk = 0; kk < 16; ++kk) {
                const float w2 = F2h[jp * DM + 64 * kk + lane];
                y[0][kk] = fmaf(h0, w2, y[0][kk]);
                y[1][kk] = fmaf(h1, w2, y[1][kk]);
                y[2][kk] = fmaf(h2, w2, y[2][kk]);
                y[3][kk] = fmaf(h3, w2, y[3][kk]);
            }
        }

        // scatter-add into the selected token's output row
#pragma unroll
        for (int i = 0; i < 4; ++i) {
            float* op = out + (size_t)(gs[i] * TG + tok[i]) * DM + lane;
#pragma unroll
            for (int kk = 0; kk < 16; ++kk)
                unsafeAtomicAdd(op + 64 * kk, y[i][kk]);
        }
    }
}

// ---------------------------------------------------------------------------
extern "C" void kernel_launch(void* const* d_in, const int* in_sizes, int n_in,
                              void* d_out, int out_size, void* d_ws, size_t ws_size,
                              hipStream_t stream) {
    (void)in_sizes; (void)n_in; (void)ws_size;
    const float* x    = (const float*)d_in[0];
    const float* ctrl = (const float*)d_in[1];
    const float* f1   = (const float*)d_in[2];
    const float* bias = (const float*)d_in[3];
    const float* f2   = (const float*)d_in[4];
    float* out = (float*)d_out;
    int*   idx = (int*)d_ws;   // 256*128*4 = 128 KB

    hipMemsetAsync(d_out, 0, (size_t)out_size * sizeof(float), stream);

    ka_logits_argmax<<<NGROUP, 512, 0, stream>>>(x, ctrl, idx);

    const size_t lds = (size_t)(FHALF * 1028 + FHALF * DM) * sizeof(float);
    hipFuncSetAttribute((const void*)kb_ffn_scatter,
                        hipFuncAttributeMaxDynamicSharedMemorySize, (int)lds);
    kb_ffn_scatter<<<NSLOT * 2, 1024, lds, stream>>>(x, f1, bias, f2, idx, out);
}

// Round 2
// 346.780 us; speedup vs baseline: 3.4072x; 3.4072x over previous
//
#include <hip/hip_runtime.h>
#include <hip/hip_bf16.h>

#define NGROUP 256   // B * (SEQ/TG)
#define NSLOT  128   // experts * sets
#define TG     32    // tokens per group
#define DM     1024  // model dim
#define FF     32    // expert size

typedef unsigned int  uint;
typedef unsigned short ushort;

__device__ __forceinline__ ushort f2bf(float f) {
    uint u = __float_as_uint(f);
    u += 0x7FFFu + ((u >> 16) & 1u);   // round-to-nearest-even
    return (ushort)(u >> 16);
}
__device__ __forceinline__ float bflo(uint u) { return __uint_as_float(u << 16); }
__device__ __forceinline__ float bfhi(uint u) { return __uint_as_float(u & 0xFFFF0000u); }

// ---------------------------------------------------------------------------
// K0: cast f2 (fp32) -> f2b (bf16).  4.2M elements, 8 per thread.
// ---------------------------------------------------------------------------
__global__ __launch_bounds__(256) void k_cast_f2(
    const float* __restrict__ f2, ushort* __restrict__ f2b)
{
    const int i = (blockIdx.x * 256 + threadIdx.x) * 8;
    const float4 a = *(const float4*)(f2 + i);
    const float4 b = *(const float4*)(f2 + i + 4);
    uint4 o;
    o.x = (uint)f2bf(a.x) | ((uint)f2bf(a.y) << 16);
    o.y = (uint)f2bf(a.z) | ((uint)f2bf(a.w) << 16);
    o.z = (uint)f2bf(b.x) | ((uint)f2bf(b.y) << 16);
    o.w = (uint)f2bf(b.z) | ((uint)f2bf(b.w) << 16);
    *(uint4*)(f2b + i) = o;
}

// ---------------------------------------------------------------------------
// K1: controller logits + tie-broken argmax. fp32 (precision-critical).
// grid = 256 groups, 512 threads. x group staged in LDS (128 KB).
// Thread tile: 2 tokens x 4 slots. LDS: Lx[32][1024] + Ls[32][128].
// ---------------------------------------------------------------------------
__global__ __launch_bounds__(512) void k_logits_argmax(
    const float* __restrict__ x, const float* __restrict__ ctrl,
    int* __restrict__ idx)
{
    extern __shared__ float sm1[];
    float* Lx = sm1;            // [32][1024]
    float* Ls = sm1 + 32768;    // [32][128]

    const int g = blockIdx.x;
    const float* xg = x + (size_t)g * TG * DM;
    for (int i = threadIdx.x * 4; i < TG * DM; i += 512 * 4)
        *(float4*)&Lx[i] = *(const float4*)&xg[i];
    __syncthreads();

    const int ng = threadIdx.x & 31;   // slots ng*4 .. ng*4+3
    const int tg = threadIdx.x >> 5;   // tokens tg*2, tg*2+1

    float a0[4] = {0.f, 0.f, 0.f, 0.f};
    float a1[4] = {0.f, 0.f, 0.f, 0.f};

    for (int k = 0; k < DM; k += 4) {
        float xa[4], xb[4];
        *(float4*)xa = *(const float4*)&Lx[(tg * 2 + 0) * DM + k];
        *(float4*)xb = *(const float4*)&Lx[(tg * 2 + 1) * DM + k];
#pragma unroll
        for (int q = 0; q < 4; ++q) {
            float c[4];
            *(float4*)c = *(const float4*)&ctrl[(size_t)(k + q) * NSLOT + ng * 4];
#pragma unroll
            for (int j = 0; j < 4; ++j) {
                a0[j] = fmaf(xa[q], c[j], a0[j]);
                a1[j] = fmaf(xb[q], c[j], a1[j]);
            }
        }
    }
#pragma unroll
    for (int j = 0; j < 4; ++j) {
        Ls[(tg * 2 + 0) * NSLOT + ng * 4 + j] = a0[j];
        Ls[(tg * 2 + 1) * NSLOT + ng * 4 + j] = a1[j];
    }
    __syncthreads();

    if (threadIdx.x < NSLOT) {
        const int n = threadIdx.x;
        float best = -1e30f;
        int bi = 0;
#pragma unroll
        for (int t = 0; t < TG; ++t) {
            const float v = Ls[t * NSLOT + n] + (float)t * (1e-6f / 31.0f);
            if (v >= best) { best = v; bi = t; }   // later token wins ties
        }
        idx[g * NSLOT + n] = bi;
    }
}

// ---------------------------------------------------------------------------
// K2: inner activations H = relu(x_gathered @ f1 + bias), stored bf16.
// grid = 128 slots x 2 group-halves = 256 blocks, 512 threads.
// LDS: F1s[1024][32] fp32 (128 KB). Wave: 16 groups, 8-way register blocked.
// Lane: j = lane&31 (f index), c = lane>>5 (d half), shfl reduce.
// ---------------------------------------------------------------------------
__global__ __launch_bounds__(512) void k_h(
    const float* __restrict__ x, const float* __restrict__ f1,
    const float* __restrict__ bias, const int* __restrict__ idx,
    ushort* __restrict__ Hb)
{
    extern __shared__ float F1s[];   // [1024][32]
    const int es = blockIdx.x >> 1;
    const int gh = blockIdx.x & 1;

    for (int i = threadIdx.x * 4; i < DM * FF; i += 512 * 4) {
        const int d = i >> 5, j = i & 31;
        *(float4*)&F1s[i] = *(const float4*)&f1[(size_t)d * (NSLOT * FF / 4) * 4 + es * FF + j];
    }
    __syncthreads();

    const int wv = threadIdx.x >> 6;
    const int lane = threadIdx.x & 63;
    const int j = lane & 31, c = lane >> 5;
    const float b = bias[es * FF + j];
    const int g0 = gh * 128 + wv * 16;

    for (int p = 0; p < 2; ++p) {
        const float* xr[8];
        int gg[8];
#pragma unroll
        for (int i = 0; i < 8; ++i) {
            gg[i] = g0 + p * 8 + i;
            const int tok = idx[gg[i] * NSLOT + es];
            xr[i] = x + ((size_t)gg[i] * TG + tok) * DM + c * 512;
        }
        float h[8] = {0.f, 0.f, 0.f, 0.f, 0.f, 0.f, 0.f, 0.f};
        for (int s = 0; s < 512; s += 4) {
            const float w0 = F1s[(c * 512 + s + 0) * FF + j];
            const float w1 = F1s[(c * 512 + s + 1) * FF + j];
            const float w2 = F1s[(c * 512 + s + 2) * FF + j];
            const float w3 = F1s[(c * 512 + s + 3) * FF + j];
#pragma unroll
            for (int i = 0; i < 8; ++i) {
                const float4 xv = *(const float4*)(xr[i] + s);
                float hh = h[i];
                hh = fmaf(xv.x, w0, hh);
                hh = fmaf(xv.y, w1, hh);
                hh = fmaf(xv.z, w2, hh);
                hh = fmaf(xv.w, w3, hh);
                h[i] = hh;
            }
        }
#pragma unroll
        for (int i = 0; i < 8; ++i) {
            float hh = h[i] + __shfl_xor(h[i], 32);
            hh = fmaxf(hh + b, 0.0f);
            if (c == 0) Hb[(size_t)gg[i] * (NSLOT * FF) + es * FF + j] = f2bf(hh);
        }
    }
}

// ---------------------------------------------------------------------------
// K4: out[g,t,d] = sum_es [idx[g,es]==t] (H[g,es,:] . f2b[es,:,d])
// grid = 32 group-octets x 8 d-eighths = 256 blocks, 512 threads (wave = group).
// LDS: OL[8][32][128] fp32 accumulator (128 KB) + idx_s[8][128] (4 KB).
// No atomics: each wave owns its group's 32 token rows; es loop is sequential.
// ---------------------------------------------------------------------------
__global__ __launch_bounds__(512) void k_out(
    const ushort* __restrict__ Hb, const ushort* __restrict__ f2b,
    const int* __restrict__ idx, float* __restrict__ out)
{
    extern __shared__ char smraw[];
    float* OL  = (float*)smraw;              // [8][32][128]
    int* idxs  = (int*)(smraw + 131072);     // [8][128]

    const int go = blockIdx.x >> 3;
    const int dq = blockIdx.x & 7;
    const int d0 = dq * 128;
    const int w = threadIdx.x >> 6;
    const int lane = threadIdx.x & 63;

    for (int i = threadIdx.x * 4; i < 8 * TG * 128; i += 512 * 4)
        *(float4*)&OL[i] = make_float4(0.f, 0.f, 0.f, 0.f);
    for (int i = threadIdx.x; i < 8 * NSLOT; i += 512)
        idxs[i] = idx[go * 8 * NSLOT + i];
    __syncthreads();

    const int g = go * 8 + w;
    const ushort* hbase = Hb + (size_t)g * (NSLOT * FF);
    float* olw = OL + w * (TG * 128);

    for (int es = 0; es < NSLOT; ++es) {
        const int t = idxs[w * NSLOT + es];
        uint hu[16];
        {
            const uint4 q0 = *(const uint4*)(hbase + es * FF);
            const uint4 q1 = *(const uint4*)(hbase + es * FF + 8);
            const uint4 q2 = *(const uint4*)(hbase + es * FF + 16);
            const uint4 q3 = *(const uint4*)(hbase + es * FF + 24);
            hu[0]=q0.x; hu[1]=q0.y; hu[2]=q0.z; hu[3]=q0.w;
            hu[4]=q1.x; hu[5]=q1.y; hu[6]=q1.z; hu[7]=q1.w;
            hu[8]=q2.x; hu[9]=q2.y; hu[10]=q2.z; hu[11]=q2.w;
            hu[12]=q3.x; hu[13]=q3.y; hu[14]=q3.z; hu[15]=q3.w;
        }
        const ushort* w2 = f2b + (size_t)es * (FF * DM) + d0 + 2 * lane;
        float y0 = 0.f, y1 = 0.f;
#pragma unroll
        for (int p = 0; p < 16; ++p) {
            const uint hp = hu[p];
            const float hA = bflo(hp), hB = bfhi(hp);
            const uint wA = *(const uint*)(w2 + (2 * p + 0) * DM);
            const uint wB = *(const uint*)(w2 + (2 * p + 1) * DM);
            y0 = fmaf(hA, bflo(wA), y0);
            y1 = fmaf(hA, bfhi(wA), y1);
            y0 = fmaf(hB, bflo(wB), y0);
            y1 = fmaf(hB, bfhi(wB), y1);
        }
        float* olp = olw + t * 128 + 2 * lane;
        olp[0] += y0;
        olp[1] += y1;
    }

    // write out (each (g,t,d) exactly once across the grid)
#pragma unroll 4
    for (int t = 0; t < TG; ++t) {
        const float2 v = *(float2*)&olw[t * 128 + 2 * lane];
        *(float2*)&out[((size_t)g * TG + t) * DM + d0 + 2 * lane] = v;
    }
}

// ---------------------------------------------------------------------------
extern "C" void kernel_launch(void* const* d_in, const int* in_sizes, int n_in,
                              void* d_out, int out_size, void* d_ws, size_t ws_size,
                              hipStream_t stream) {
    (void)in_sizes; (void)n_in; (void)out_size; (void)ws_size;
    const float* x    = (const float*)d_in[0];
    const float* ctrl = (const float*)d_in[1];
    const float* f1   = (const float*)d_in[2];
    const float* bias = (const float*)d_in[3];
    const float* f2   = (const float*)d_in[4];
    float* out = (float*)d_out;

    char* ws = (char*)d_ws;
    int*    idx = (int*)ws;                               // 128 KB
    ushort* Hb  = (ushort*)(ws + 131072);                 // 2 MB
    ushort* f2b = (ushort*)(ws + 131072 + 2097152);       // 8 MB

    k_cast_f2<<<(NSLOT * FF * DM) / (256 * 8), 256, 0, stream>>>(f2, f2b);

    const size_t lds1 = (size_t)(TG * DM + TG * NSLOT) * sizeof(float);   // 147456
    hipFuncSetAttribute((const void*)k_logits_argmax,
                        hipFuncAttributeMaxDynamicSharedMemorySize, (int)lds1);
    k_logits_argmax<<<NGROUP, 512, lds1, stream>>>(x, ctrl, idx);

    const size_t lds2 = (size_t)(DM * FF) * sizeof(float);                // 131072
    hipFuncSetAttribute((const void*)k_h,
                        hipFuncAttributeMaxDynamicSharedMemorySize, (int)lds2);
    k_h<<<NSLOT * 2, 512, lds2, stream>>>(x, f1, bias, idx, Hb);

    const size_t lds4 = 131072 + 4096;                                    // 135168
    hipFuncSetAttribute((const void*)k_out,
                        hipFuncAttributeMaxDynamicSharedMemorySize, (int)lds4);
    k_out<<<NGROUP, 512, lds4, stream>>>(Hb, f2b, idx, out);
}

// Round 3
// 166.334 us; speedup vs baseline: 7.1035x; 2.0848x over previous
//
#include <hip/hip_runtime.h>
#include <hip/hip_bf16.h>

#define NGROUP 256   // B * (SEQ/TG)
#define NSLOT  128   // experts * sets (n = e*4 + s, matches all input strides)
#define TG     32    // tokens per group
#define DM     1024  // model dim
#define FF     32    // expert size

typedef unsigned int  uint;
typedef unsigned short ushort;
typedef __attribute__((ext_vector_type(4))) float f32x4;
typedef __attribute__((ext_vector_type(8))) short bf16x8;

__device__ __forceinline__ ushort f2bf(float f) {
    uint u = __float_as_uint(f);
    u += 0x7FFFu + ((u >> 16) & 1u);   // RNE
    return (ushort)(u >> 16);
}
__device__ __forceinline__ uint pk2(float a, float b) {
    return (uint)f2bf(a) | ((uint)f2bf(b) << 16);
}

// ---------------------------------------------------------------------------
// K0: weight prep.
//  blocks 0..127   : f1[d][es][f] -> f1T[es][f][d]  (bf16, MFMA-B layout)
//  blocks 128..255 : f2[es][f][d] -> f2T[es][d][f]  (bf16, MFMA-A layout)
// LDS 64x33 fp32 transpose tile; coalesced global reads and writes.
// ---------------------------------------------------------------------------
__global__ __launch_bounds__(256) void k_prep(
    const float* __restrict__ f1, const float* __restrict__ f2,
    ushort* __restrict__ f1T, ushort* __restrict__ f2T)
{
    __shared__ float Ltr[64 * 33];
    const int t = threadIdx.x;
    if (blockIdx.x < 128) {
        const int es = blockIdx.x;
        for (int d0 = 0; d0 < DM; d0 += 64) {
            const int dd = t >> 2, f0 = (t & 3) * 8;
            const float* src = f1 + (size_t)(d0 + dd) * 4096 + es * FF + f0;
            float4 a = *(const float4*)src;
            float4 b = *(const float4*)(src + 4);
            __syncthreads();
            float* Lp = &Ltr[dd * 33 + f0];
            Lp[0] = a.x; Lp[1] = a.y; Lp[2] = a.z; Lp[3] = a.w;
            Lp[4] = b.x; Lp[5] = b.y; Lp[6] = b.z; Lp[7] = b.w;
            __syncthreads();
            const int f = t >> 3, dd8 = (t & 7) * 8;
            uint4 o;
            o.x = pk2(Ltr[(dd8 + 0) * 33 + f], Ltr[(dd8 + 1) * 33 + f]);
            o.y = pk2(Ltr[(dd8 + 2) * 33 + f], Ltr[(dd8 + 3) * 33 + f]);
            o.z = pk2(Ltr[(dd8 + 4) * 33 + f], Ltr[(dd8 + 5) * 33 + f]);
            o.w = pk2(Ltr[(dd8 + 6) * 33 + f], Ltr[(dd8 + 7) * 33 + f]);
            *(uint4*)(f1T + (size_t)es * (FF * DM) + f * DM + d0 + dd8) = o;
        }
    } else {
        const int es = blockIdx.x - 128;
        for (int d0 = 0; d0 < DM; d0 += 64) {
            const int f = t >> 3, ds = (t & 7) * 8;
            const float* src = f2 + (size_t)es * (FF * DM) + f * DM + d0 + ds;
            float4 a = *(const float4*)src;
            float4 b = *(const float4*)(src + 4);
            __syncthreads();
            Ltr[(ds + 0) * 33 + f] = a.x; Ltr[(ds + 1) * 33 + f] = a.y;
            Ltr[(ds + 2) * 33 + f] = a.z; Ltr[(ds + 3) * 33 + f] = a.w;
            Ltr[(ds + 4) * 33 + f] = b.x; Ltr[(ds + 5) * 33 + f] = b.y;
            Ltr[(ds + 6) * 33 + f] = b.z; Ltr[(ds + 7) * 33 + f] = b.w;
            __syncthreads();
            const int dd = t >> 2, f0 = (t & 3) * 8;
            uint4 o;
            o.x = pk2(Ltr[dd * 33 + f0 + 0], Ltr[dd * 33 + f0 + 1]);
            o.y = pk2(Ltr[dd * 33 + f0 + 2], Ltr[dd * 33 + f0 + 3]);
            o.z = pk2(Ltr[dd * 33 + f0 + 4], Ltr[dd * 33 + f0 + 5]);
            o.w = pk2(Ltr[dd * 33 + f0 + 6], Ltr[dd * 33 + f0 + 7]);
            *(uint4*)(f2T + (size_t)es * (FF * DM) + (d0 + dd) * FF + f0) = o;
        }
    }
}

// ---------------------------------------------------------------------------
// K1: controller logits + tie-broken argmax. fp32, UNCHANGED from v2
// (bit-identical accumulation order — proven to match the np argmax).
// ---------------------------------------------------------------------------
__global__ __launch_bounds__(512) void k_logits_argmax(
    const float* __restrict__ x, const float* __restrict__ ctrl,
    int* __restrict__ idx)
{
    extern __shared__ float sm1[];
    float* Lx = sm1;            // [32][1024]
    float* Ls = sm1 + 32768;    // [32][128]

    const int g = blockIdx.x;
    const float* xg = x + (size_t)g * TG * DM;
    for (int i = threadIdx.x * 4; i < TG * DM; i += 512 * 4)
        *(float4*)&Lx[i] = *(const float4*)&xg[i];
    __syncthreads();

    const int ng = threadIdx.x & 31;
    const int tg = threadIdx.x >> 5;

    float a0[4] = {0.f, 0.f, 0.f, 0.f};
    float a1[4] = {0.f, 0.f, 0.f, 0.f};

    for (int k = 0; k < DM; k += 4) {
        float xa[4], xb[4];
        *(float4*)xa = *(const float4*)&Lx[(tg * 2 + 0) * DM + k];
        *(float4*)xb = *(const float4*)&Lx[(tg * 2 + 1) * DM + k];
#pragma unroll
        for (int q = 0; q < 4; ++q) {
            float c[4];
            *(float4*)c = *(const float4*)&ctrl[(size_t)(k + q) * NSLOT + ng * 4];
#pragma unroll
            for (int j = 0; j < 4; ++j) {
                a0[j] = fmaf(xa[q], c[j], a0[j]);
                a1[j] = fmaf(xb[q], c[j], a1[j]);
            }
        }
    }
#pragma unroll
    for (int j = 0; j < 4; ++j) {
        Ls[(tg * 2 + 0) * NSLOT + ng * 4 + j] = a0[j];
        Ls[(tg * 2 + 1) * NSLOT + ng * 4 + j] = a1[j];
    }
    __syncthreads();

    if (threadIdx.x < NSLOT) {
        const int n = threadIdx.x;
        float best = -1e30f;
        int bi = 0;
#pragma unroll
        for (int t = 0; t < TG; ++t) {
            const float v = Ls[t * NSLOT + n] + (float)t * (1e-6f / 31.0f);
            if (v >= best) { best = v; bi = t; }
        }
        idx[g * NSLOT + n] = bi;
    }
}

// ---------------------------------------------------------------------------
// K2: H = relu(x_gathered @ f1 + bias) via MFMA 16x16x32 bf16.
// grid = 128 es x 2 M-halves = 256 blocks, 256 thr (4 waves).
// B (f1 slice) in XOR-swizzled LDS [32f][1024k] bf16 (64 KB -> 2 blocks/CU);
// A = gathered x rows, fp32 global -> bf16 pack in-register.
// Wave w: groups gh*128 + w*32 + mt*16, mt=0..1; acc[2 mt][2 nt].
// ---------------------------------------------------------------------------
__global__ __launch_bounds__(256) void k_h_mfma(
    const float* __restrict__ x, const ushort* __restrict__ f1T,
    const float* __restrict__ bias, const int* __restrict__ idx,
    ushort* __restrict__ Hb)
{
    extern __shared__ char smK2[];
    ushort* F1 = (ushort*)smK2;   // swizzled [32][1024] bf16

    const int es = blockIdx.x >> 1;
    const int gh = blockIdx.x & 1;

    {
        const ushort* src = f1T + (size_t)es * (FF * DM);
        for (int e = threadIdx.x * 8; e < FF * DM; e += 256 * 8) {
            uint4 v = *(const uint4*)(src + e);
            const int f = e >> 10, k = e & 1023;
            const int byt = f * 2048 + ((k * 2) ^ ((f & 7) << 4));
            *(uint4*)(smK2 + byt) = v;
        }
    }
    __syncthreads();

    const int w = threadIdx.x >> 6;
    const int lane = threadIdx.x & 63;
    const int lrow = lane & 15;
    const int lk8 = (lane >> 4) * 8;

    const float* abase[2];
#pragma unroll
    for (int mt = 0; mt < 2; ++mt) {
        const int g = gh * 128 + w * 32 + mt * 16 + lrow;
        const int tok = idx[g * NSLOT + es];
        abase[mt] = x + ((size_t)g * TG + tok) * DM + lk8;
    }

    f32x4 acc[2][2];
#pragma unroll
    for (int mt = 0; mt < 2; ++mt)
#pragma unroll
        for (int nt = 0; nt < 2; ++nt) acc[mt][nt] = (f32x4){0.f, 0.f, 0.f, 0.f};

#pragma unroll 2
    for (int k0 = 0; k0 < DM; k0 += 32) {
        bf16x8 bfr[2];
#pragma unroll
        for (int nt = 0; nt < 2; ++nt) {
            const int f = nt * 16 + lrow;
            const int k = k0 + lk8;
            bfr[nt] = *(const bf16x8*)(smK2 + f * 2048 + ((k * 2) ^ ((f & 7) << 4)));
        }
#pragma unroll
        for (int mt = 0; mt < 2; ++mt) {
            const float4 u = *(const float4*)(abase[mt] + k0);
            const float4 v = *(const float4*)(abase[mt] + k0 + 4);
            union { bf16x8 bv; uint u32[4]; } A;
            A.u32[0] = pk2(u.x, u.y);
            A.u32[1] = pk2(u.z, u.w);
            A.u32[2] = pk2(v.x, v.y);
            A.u32[3] = pk2(v.z, v.w);
#pragma unroll
            for (int nt = 0; nt < 2; ++nt)
                acc[mt][nt] = __builtin_amdgcn_mfma_f32_16x16x32_bf16(
                    A.bv, bfr[nt], acc[mt][nt], 0, 0, 0);
        }
    }

    // epilogue: D col = lane&15 (f within N-tile), row = (lane>>4)*4+r (group)
#pragma unroll
    for (int nt = 0; nt < 2; ++nt) {
        const int f = nt * 16 + lrow;
        const float bv = bias[es * FF + f];
#pragma unroll
        for (int mt = 0; mt < 2; ++mt) {
#pragma unroll
            for (int r = 0; r < 4; ++r) {
                const int g = gh * 128 + w * 32 + mt * 16 + (lane >> 4) * 4 + r;
                const float hv = fmaxf(acc[mt][nt][r] + bv, 0.0f);
                Hb[(size_t)g * (NSLOT * FF) + es * FF + f] = f2bf(hv);
            }
        }
    }
}

// ---------------------------------------------------------------------------
// K3: out[g,t,:] += sum_es [idx==t] H[g,es,:] @ f2[es].  MFMA per es:
// M=16 d-rows, N=16 groups, K=32 f (no waste). grid = 16 gb x 16 db = 256
// blocks, 256 thr (4 waves, wave = 16-d M-tile). D-frag scatter-accumulated
// into padded LDS OL[16][32*64+4] (2-way banks, race-free: waves own disjoint
// d, es sequential). f2T slices double-buffered 2-es-per-phase.
// ---------------------------------------------------------------------------
__global__ __launch_bounds__(256) void k_out_mfma(
    const ushort* __restrict__ Hb, const ushort* __restrict__ f2T,
    const int* __restrict__ idx, float* __restrict__ out)
{
    extern __shared__ char smK3[];
    float* OL   = (float*)smK3;                 // [16][2052] = 131328 B
    char* Ab    = smK3 + 131328;                // [4][64][40] bf16 = 20480 B
    int* idxs_t = (int*)(smK3 + 131328 + 20480); // [128][16]    = 8192 B

    const int G0 = (blockIdx.x >> 4) * 16;
    const int D0 = (blockIdx.x & 15) * 64;
    const int tid = threadIdx.x;
    const int w = tid >> 6;
    const int lane = tid & 63;
    const int gl = lane & 15;
    const int lk8 = (lane >> 4) * 8;

    // zero OL (16*2052 = 32832 dwords), load idx transposed
    for (int i = tid * 4; i < 32768; i += 1024)
        *(f32x4*)&OL[i] = (f32x4){0.f, 0.f, 0.f, 0.f};
    if (tid < 16) *(f32x4*)&OL[32768 + tid * 4] = (f32x4){0.f, 0.f, 0.f, 0.f};
    for (int i = tid; i < NSLOT * 16; i += 256)
        idxs_t[i] = idx[(G0 + (i & 15)) * NSLOT + (i >> 4)];

    // prologue: stage es 0,1 into buffers 0,1
    {
        const int e = tid * 8;
        const int dd = e >> 5, f0 = e & 31;
#pragma unroll
        for (int esi = 0; esi < 2; ++esi) {
            uint4 v = *(const uint4*)(f2T + (size_t)esi * (FF * DM) + D0 * FF + e);
            *(uint4*)(Ab + esi * 5120 + dd * 80 + f0 * 2) = v;
        }
    }
    __syncthreads();

    for (int p = 0; p < 64; ++p) {
        const int cur = p & 1;
        if (p < 63) {
            const int e = tid * 8;
            const int dd = e >> 5, f0 = e & 31;
#pragma unroll
            for (int esi = 0; esi < 2; ++esi) {
                const int es2 = 2 * p + 2 + esi;
                uint4 v = *(const uint4*)(f2T + (size_t)es2 * (FF * DM) + D0 * FF + e);
                *(uint4*)(Ab + ((cur ^ 1) * 2 + esi) * 5120 + dd * 80 + f0 * 2) = v;
            }
        }
#pragma unroll
        for (int esi = 0; esi < 2; ++esi) {
            const int es = 2 * p + esi;
            // B: H rows for 16 groups (col = gl, k = f)
            const bf16x8 bfr = *(const bf16x8*)(
                Hb + (size_t)(G0 + gl) * (NSLOT * FF) + es * FF + lk8);
            // A: f2T slice from LDS (row = d-local, k = f)
            const bf16x8 afr = *(const bf16x8*)(
                Ab + (cur * 2 + esi) * 5120 + (w * 16 + (lane & 15)) * 80 + lk8 * 2);
            f32x4 d = __builtin_amdgcn_mfma_f32_16x16x32_bf16(
                afr, bfr, (f32x4){0.f, 0.f, 0.f, 0.f}, 0, 0, 0);
            // scatter-accumulate: col = gl -> token row, rows = d
            const int t = idxs_t[es * 16 + gl];
            const int dloc = w * 16 + (lane >> 4) * 4;
            float* olp = &OL[gl * 2052 + t * 64 + dloc];
            f32x4 old = *(const f32x4*)olp;
            *(f32x4*)olp = old + d;
        }
        __syncthreads();
    }

    // dense write-out: every (g, t, d) exactly once
    for (int it = 0; it < 32; ++it) {
        const int flat = tid * 4 + it * 1024;
        const int gli = flat >> 11, rem = flat & 2047;
        const int t = rem >> 6, d = rem & 63;
        const f32x4 v = *(const f32x4*)&OL[gli * 2052 + rem];
        *(f32x4*)&out[((size_t)(G0 + gli) * TG + t) * DM + D0 + d] = v;
    }
}

// ---------------------------------------------------------------------------
extern "C" void kernel_launch(void* const* d_in, const int* in_sizes, int n_in,
                              void* d_out, int out_size, void* d_ws, size_t ws_size,
                              hipStream_t stream) {
    (void)in_sizes; (void)n_in; (void)out_size; (void)ws_size;
    const float* x    = (const float*)d_in[0];
    const float* ctrl = (const float*)d_in[1];
    const float* f1   = (const float*)d_in[2];
    const float* bias = (const float*)d_in[3];
    const float* f2   = (const float*)d_in[4];
    float* out = (float*)d_out;

    char* ws = (char*)d_ws;
    int*    idx = (int*)ws;                         // 128 KB
    ushort* Hb  = (ushort*)(ws + 131072);           // 2 MB
    ushort* f1T = (ushort*)(ws + 2228224);          // 8 MB
    ushort* f2T = (ushort*)(ws + 10616832);         // 8 MB (end ~18.1 MB)

    k_prep<<<256, 256, 0, stream>>>(f1, f2, f1T, f2T);

    const size_t lds1 = (size_t)(TG * DM + TG * NSLOT) * sizeof(float);  // 147456
    hipFuncSetAttribute((const void*)k_logits_argmax,
                        hipFuncAttributeMaxDynamicSharedMemorySize, (int)lds1);
    k_logits_argmax<<<NGROUP, 512, lds1, stream>>>(x, ctrl, idx);

    const size_t lds2 = 65536;
    hipFuncSetAttribute((const void*)k_h_mfma,
                        hipFuncAttributeMaxDynamicSharedMemorySize, (int)lds2);
    k_h_mfma<<<NSLOT * 2, 256, lds2, stream>>>(x, f1T, bias, idx, Hb);

    const size_t lds3 = 131328 + 20480 + 8192;      // 160000
    hipFuncSetAttribute((const void*)k_out_mfma,
                        hipFuncAttributeMaxDynamicSharedMemorySize, (int)lds3);
    k_out_mfma<<<256, 256, lds3, stream>>>(Hb, f2T, idx, out);
}

// Round 4
// 123.079 us; speedup vs baseline: 9.6000x; 1.3514x over previous
//
#include <hip/hip_runtime.h>
#include <hip/hip_bf16.h>

#define NGROUP 256   // B * (SEQ/TG)
#define NSLOT  128   // experts * sets
#define TG     32    // tokens per group
#define DM     1024  // model dim
#define FF     32    // expert size

#define LSCALE     4096.0f
#define INV_LSCALE (1.0f / 4096.0f)

typedef unsigned int  uint;
typedef unsigned short ushort;
typedef __attribute__((ext_vector_type(4))) float f32x4;
typedef __attribute__((ext_vector_type(8))) short bf16x8;
typedef __attribute__((ext_vector_type(8))) _Float16 f16x8;

__device__ __forceinline__ ushort f2bf(float f) {
    uint u = __float_as_uint(f);
    u += 0x7FFFu + ((u >> 16) & 1u);   // RNE
    return (ushort)(u >> 16);
}
__device__ __forceinline__ uint pk2(float a, float b) {
    return (uint)f2bf(a) | ((uint)f2bf(b) << 16);
}

// ---------------------------------------------------------------------------
// K0: prep.
//  blocks 0..127   : f1[d][es][f] -> f1T[es][f][d]  bf16 (MFMA-B layout)
//  blocks 128..255 : f2[es][f][d] -> f2T[es][d][f]  bf16 (MFMA-A layout)
//  blocks 256..383 : x -> xb bf16 (straight cast, RNE — matches old in-reg pk2)
//  blocks 384..391 : ctrl -> cFh/cFl fp16 split, MFMA-fragment order
// ---------------------------------------------------------------------------
__global__ __launch_bounds__(256) void k_prep(
    const float* __restrict__ f1, const float* __restrict__ f2,
    const float* __restrict__ x, const float* __restrict__ ctrl,
    ushort* __restrict__ f1T, ushort* __restrict__ f2T,
    ushort* __restrict__ xb, ushort* __restrict__ cFh, ushort* __restrict__ cFl)
{
    __shared__ float Ltr[64 * 33];
    const int t = threadIdx.x;
    if (blockIdx.x < 128) {
        const int es = blockIdx.x;
        for (int d0 = 0; d0 < DM; d0 += 64) {
            const int dd = t >> 2, f0 = (t & 3) * 8;
            const float* src = f1 + (size_t)(d0 + dd) * 4096 + es * FF + f0;
            float4 a = *(const float4*)src;
            float4 b = *(const float4*)(src + 4);
            __syncthreads();
            float* Lp = &Ltr[dd * 33 + f0];
            Lp[0] = a.x; Lp[1] = a.y; Lp[2] = a.z; Lp[3] = a.w;
            Lp[4] = b.x; Lp[5] = b.y; Lp[6] = b.z; Lp[7] = b.w;
            __syncthreads();
            const int f = t >> 3, dd8 = (t & 7) * 8;
            uint4 o;
            o.x = pk2(Ltr[(dd8 + 0) * 33 + f], Ltr[(dd8 + 1) * 33 + f]);
            o.y = pk2(Ltr[(dd8 + 2) * 33 + f], Ltr[(dd8 + 3) * 33 + f]);
            o.z = pk2(Ltr[(dd8 + 4) * 33 + f], Ltr[(dd8 + 5) * 33 + f]);
            o.w = pk2(Ltr[(dd8 + 6) * 33 + f], Ltr[(dd8 + 7) * 33 + f]);
            *(uint4*)(f1T + (size_t)es * (FF * DM) + f * DM + d0 + dd8) = o;
        }
    } else if (blockIdx.x < 256) {
        const int es = blockIdx.x - 128;
        for (int d0 = 0; d0 < DM; d0 += 64) {
            const int f = t >> 3, ds = (t & 7) * 8;
            const float* src = f2 + (size_t)es * (FF * DM) + f * DM + d0 + ds;
            float4 a = *(const float4*)src;
            float4 b = *(const float4*)(src + 4);
            __syncthreads();
            Ltr[(ds + 0) * 33 + f] = a.x; Ltr[(ds + 1) * 33 + f] = a.y;
            Ltr[(ds + 2) * 33 + f] = a.z; Ltr[(ds + 3) * 33 + f] = a.w;
            Ltr[(ds + 4) * 33 + f] = b.x; Ltr[(ds + 5) * 33 + f] = b.y;
            Ltr[(ds + 6) * 33 + f] = b.z; Ltr[(ds + 7) * 33 + f] = b.w;
            __syncthreads();
            const int dd = t >> 2, f0 = (t & 3) * 8;
            uint4 o;
            o.x = pk2(Ltr[dd * 33 + f0 + 0], Ltr[dd * 33 + f0 + 1]);
            o.y = pk2(Ltr[dd * 33 + f0 + 2], Ltr[dd * 33 + f0 + 3]);
            o.z = pk2(Ltr[dd * 33 + f0 + 4], Ltr[dd * 33 + f0 + 5]);
            o.w = pk2(Ltr[dd * 33 + f0 + 6], Ltr[dd * 33 + f0 + 7]);
            *(uint4*)(f2T + (size_t)es * (FF * DM) + (d0 + dd) * FF + f0) = o;
        }
    } else if (blockIdx.x < 384) {
        // x -> bf16, 65536 elements per block
        const size_t xoff = (size_t)(blockIdx.x - 256) * 65536;
        for (int e = t * 8; e < 65536; e += 256 * 8) {
            const float4 a = *(const float4*)(x + xoff + e);
            const float4 b = *(const float4*)(x + xoff + e + 4);
            uint4 o;
            o.x = pk2(a.x, a.y); o.y = pk2(a.z, a.w);
            o.z = pk2(b.x, b.y); o.w = pk2(b.z, b.w);
            *(uint4*)(xb + xoff + e) = o;
        }
    } else {
        // ctrl -> fp16 hi/lo in fragment order:
        // octet o: lane=o&63, ks=(o>>6)&31, nt=o>>11;
        // element j: k = ks*32 + (lane>>4)*8 + j, n = nt*16 + (lane&15)
        const int base_o = ((blockIdx.x - 384) * 256 + t) * 8;
#pragma unroll
        for (int q = 0; q < 8; ++q) {
            const int o = base_o + q;
            const int lane = o & 63, ks = (o >> 6) & 31, nt = o >> 11;
            const int k = ks * 32 + ((lane >> 4) << 3);
            const int n = nt * 16 + (lane & 15);
            union { f16x8 v; _Float16 e[8]; } H, L;
#pragma unroll
            for (int j = 0; j < 8; ++j) {
                const float c = ctrl[(size_t)(k + j) * NSLOT + n];
                const _Float16 h = (_Float16)c;
                H.e[j] = h;
                L.e[j] = (_Float16)((c - (float)h) * LSCALE);
            }
            *(f16x8*)(cFh + (size_t)o * 8) = H.v;
            *(f16x8*)(cFl + (size_t)o * 8) = L.v;
        }
    }
}

// ---------------------------------------------------------------------------
// K1: controller logits + tie-broken argmax via split-fp16 MFMA.
// grid = 256 groups, 256 thr (4 waves). Wave w owns K-chunk [w*256,(w+1)*256).
// L = sum xh*ch + (sum xh*cl + sum xl*ch)/4096, fp32 MFMA accumulators.
// LDS: Lp[4][32][128] fp32 partials -> tree reduce -> argmax (proven code).
// ---------------------------------------------------------------------------
__global__ __launch_bounds__(256) void k_logits_mfma(
    const float* __restrict__ x, const ushort* __restrict__ cFh,
    const ushort* __restrict__ cFl, int* __restrict__ idx)
{
    extern __shared__ float Lp[];   // [4][32][128] = 64 KB
    const int g = blockIdx.x;
    const int w = threadIdx.x >> 6;
    const int lane = threadIdx.x & 63;
    const int lrow = lane & 15;
    const int lk8 = (lane >> 4) * 8;

    const float* xr0 = x + ((size_t)g * TG + lrow) * DM + w * 256 + lk8;
    const float* xr1 = xr0 + 16 * DM;

    f32x4 ahh[2][8], ax[2][8];
#pragma unroll
    for (int mt = 0; mt < 2; ++mt)
#pragma unroll
        for (int nt = 0; nt < 8; ++nt) {
            ahh[mt][nt] = (f32x4){0.f, 0.f, 0.f, 0.f};
            ax[mt][nt]  = (f32x4){0.f, 0.f, 0.f, 0.f};
        }

    for (int ks = 0; ks < 8; ++ks) {
        f16x8 Ah[2], Al[2];
#pragma unroll
        for (int mt = 0; mt < 2; ++mt) {
            const float* p = (mt ? xr1 : xr0) + ks * 32;
            float xe[8];
            *(float4*)&xe[0] = *(const float4*)p;
            *(float4*)&xe[4] = *(const float4*)(p + 4);
            union { f16x8 v; _Float16 e[8]; } H, L;
#pragma unroll
            for (int j = 0; j < 8; ++j) {
                const _Float16 h = (_Float16)xe[j];
                H.e[j] = h;
                L.e[j] = (_Float16)((xe[j] - (float)h) * LSCALE);
            }
            Ah[mt] = H.v; Al[mt] = L.v;
        }
#pragma unroll
        for (int nt = 0; nt < 8; ++nt) {
            const size_t fo = (((size_t)nt * 32 + (w * 8 + ks)) * 64 + lane) * 8;
            const f16x8 Bh = *(const f16x8*)(cFh + fo);
            const f16x8 Bl = *(const f16x8*)(cFl + fo);
#pragma unroll
            for (int mt = 0; mt < 2; ++mt) {
                ahh[mt][nt] = __builtin_amdgcn_mfma_f32_16x16x32_f16(Ah[mt], Bh, ahh[mt][nt], 0, 0, 0);
                ax[mt][nt]  = __builtin_amdgcn_mfma_f32_16x16x32_f16(Al[mt], Bh, ax[mt][nt], 0, 0, 0);
                ax[mt][nt]  = __builtin_amdgcn_mfma_f32_16x16x32_f16(Ah[mt], Bl, ax[mt][nt], 0, 0, 0);
            }
        }
    }

    // write per-wave partial logits: row = mt*16 + (lane>>4)*4 + r, col = nt*16 + lrow
#pragma unroll
    for (int mt = 0; mt < 2; ++mt)
#pragma unroll
        for (int nt = 0; nt < 8; ++nt)
#pragma unroll
            for (int r = 0; r < 4; ++r) {
                const int trow = mt * 16 + (lane >> 4) * 4 + r;
                const int n = nt * 16 + lrow;
                Lp[(w * TG + trow) * NSLOT + n] =
                    ahh[mt][nt][r] + ax[mt][nt][r] * INV_LSCALE;
            }
    __syncthreads();

    // reduce 4 K-chunk planes into plane 0
    for (int i = threadIdx.x * 4; i < TG * NSLOT; i += 256 * 4) {
        f32x4 s0 = *(const f32x4*)&Lp[i];
        f32x4 s1 = *(const f32x4*)&Lp[4096 + i];
        f32x4 s2 = *(const f32x4*)&Lp[8192 + i];
        f32x4 s3 = *(const f32x4*)&Lp[12288 + i];
        *(f32x4*)&Lp[i] = (s0 + s1) + (s2 + s3);
    }
    __syncthreads();

    if (threadIdx.x < NSLOT) {
        const int n = threadIdx.x;
        float best = -1e30f;
        int bi = 0;
#pragma unroll
        for (int t = 0; t < TG; ++t) {
            const float v = Lp[t * NSLOT + n] + (float)t * (1e-6f / 31.0f);
            if (v >= best) { best = v; bi = t; }   // later token wins ties
        }
        idx[g * NSLOT + n] = bi;
    }
}

// ---------------------------------------------------------------------------
// K2: H = relu(x_gathered @ f1 + bias) via MFMA 16x16x32 bf16.
// A-operand now read directly from prepped bf16 xb (identical values to the
// previous in-register pk2 — numerics unchanged, half the gather bytes).
// ---------------------------------------------------------------------------
__global__ __launch_bounds__(256) void k_h_mfma(
    const ushort* __restrict__ xb, const ushort* __restrict__ f1T,
    const float* __restrict__ bias, const int* __restrict__ idx,
    ushort* __restrict__ Hb)
{
    extern __shared__ char smK2[];

    const int es = blockIdx.x >> 1;
    const int gh = blockIdx.x & 1;

    {
        const ushort* src = f1T + (size_t)es * (FF * DM);
        for (int e = threadIdx.x * 8; e < FF * DM; e += 256 * 8) {
            uint4 v = *(const uint4*)(src + e);
            const int f = e >> 10, k = e & 1023;
            const int byt = f * 2048 + ((k * 2) ^ ((f & 7) << 4));
            *(uint4*)(smK2 + byt) = v;
        }
    }
    __syncthreads();

    const int w = threadIdx.x >> 6;
    const int lane = threadIdx.x & 63;
    const int lrow = lane & 15;
    const int lk8 = (lane >> 4) * 8;

    const ushort* abase[2];
#pragma unroll
    for (int mt = 0; mt < 2; ++mt) {
        const int g = gh * 128 + w * 32 + mt * 16 + lrow;
        const int tok = idx[g * NSLOT + es];
        abase[mt] = xb + ((size_t)g * TG + tok) * DM + lk8;
    }

    f32x4 acc[2][2];
#pragma unroll
    for (int mt = 0; mt < 2; ++mt)
#pragma unroll
        for (int nt = 0; nt < 2; ++nt) acc[mt][nt] = (f32x4){0.f, 0.f, 0.f, 0.f};

#pragma unroll 2
    for (int k0 = 0; k0 < DM; k0 += 32) {
        bf16x8 bfr[2];
#pragma unroll
        for (int nt = 0; nt < 2; ++nt) {
            const int f = nt * 16 + lrow;
            const int k = k0 + lk8;
            bfr[nt] = *(const bf16x8*)(smK2 + f * 2048 + ((k * 2) ^ ((f & 7) << 4)));
        }
#pragma unroll
        for (int mt = 0; mt < 2; ++mt) {
            const bf16x8 A = *(const bf16x8*)(abase[mt] + k0);
#pragma unroll
            for (int nt = 0; nt < 2; ++nt)
                acc[mt][nt] = __builtin_amdgcn_mfma_f32_16x16x32_bf16(
                    A, bfr[nt], acc[mt][nt], 0, 0, 0);
        }
    }

#pragma unroll
    for (int nt = 0; nt < 2; ++nt) {
        const int f = nt * 16 + lrow;
        const float bv = bias[es * FF + f];
#pragma unroll
        for (int mt = 0; mt < 2; ++mt) {
#pragma unroll
            for (int r = 0; r < 4; ++r) {
                const int g = gh * 128 + w * 32 + mt * 16 + (lane >> 4) * 4 + r;
                const float hv = fmaxf(acc[mt][nt][r] + bv, 0.0f);
                Hb[(size_t)g * (NSLOT * FF) + es * FF + f] = f2bf(hv);
            }
        }
    }
}

// ---------------------------------------------------------------------------
// K3: out accumulation via per-es MFMA + LDS scatter-accumulate. UNCHANGED.
// ---------------------------------------------------------------------------
__global__ __launch_bounds__(256) void k_out_mfma(
    const ushort* __restrict__ Hb, const ushort* __restrict__ f2T,
    const int* __restrict__ idx, float* __restrict__ out)
{
    extern __shared__ char smK3[];
    float* OL   = (float*)smK3;                 // [16][2052]
    char* Ab    = smK3 + 131328;                // [4][64][40] bf16
    int* idxs_t = (int*)(smK3 + 131328 + 20480); // [128][16]

    const int G0 = (blockIdx.x >> 4) * 16;
    const int D0 = (blockIdx.x & 15) * 64;
    const int tid = threadIdx.x;
    const int w = tid >> 6;
    const int lane = tid & 63;
    const int gl = lane & 15;
    const int lk8 = (lane >> 4) * 8;

    for (int i = tid * 4; i < 32768; i += 1024)
        *(f32x4*)&OL[i] = (f32x4){0.f, 0.f, 0.f, 0.f};
    if (tid < 16) *(f32x4*)&OL[32768 + tid * 4] = (f32x4){0.f, 0.f, 0.f, 0.f};
    for (int i = tid; i < NSLOT * 16; i += 256)
        idxs_t[i] = idx[(G0 + (i & 15)) * NSLOT + (i >> 4)];

    {
        const int e = tid * 8;
        const int dd = e >> 5, f0 = e & 31;
#pragma unroll
        for (int esi = 0; esi < 2; ++esi) {
            uint4 v = *(const uint4*)(f2T + (size_t)esi * (FF * DM) + D0 * FF + e);
            *(uint4*)(Ab + esi * 5120 + dd * 80 + f0 * 2) = v;
        }
    }
    __syncthreads();

    for (int p = 0; p < 64; ++p) {
        const int cur = p & 1;
        if (p < 63) {
            const int e = tid * 8;
            const int dd = e >> 5, f0 = e & 31;
#pragma unroll
            for (int esi = 0; esi < 2; ++esi) {
                const int es2 = 2 * p + 2 + esi;
                uint4 v = *(const uint4*)(f2T + (size_t)es2 * (FF * DM) + D0 * FF + e);
                *(uint4*)(Ab + ((cur ^ 1) * 2 + esi) * 5120 + dd * 80 + f0 * 2) = v;
            }
        }
#pragma unroll
        for (int esi = 0; esi < 2; ++esi) {
            const int es = 2 * p + esi;
            const bf16x8 bfr = *(const bf16x8*)(
                Hb + (size_t)(G0 + gl) * (NSLOT * FF) + es * FF + lk8);
            const bf16x8 afr = *(const bf16x8*)(
                Ab + (cur * 2 + esi) * 5120 + (w * 16 + (lane & 15)) * 80 + lk8 * 2);
            f32x4 d = __builtin_amdgcn_mfma_f32_16x16x32_bf16(
                afr, bfr, (f32x4){0.f, 0.f, 0.f, 0.f}, 0, 0, 0);
            const int t = idxs_t[es * 16 + gl];
            const int dloc = w * 16 + (lane >> 4) * 4;
            float* olp = &OL[gl * 2052 + t * 64 + dloc];
            f32x4 old = *(const f32x4*)olp;
            *(f32x4*)olp = old + d;
        }
        __syncthreads();
    }

    for (int it = 0; it < 32; ++it) {
        const int flat = tid * 4 + it * 1024;
        const int gli = flat >> 11, rem = flat & 2047;
        const int t = rem >> 6, d = rem & 63;
        const f32x4 v = *(const f32x4*)&OL[gli * 2052 + rem];
        *(f32x4*)&out[((size_t)(G0 + gli) * TG + t) * DM + D0 + d] = v;
    }
}

// ---------------------------------------------------------------------------
extern "C" void kernel_launch(void* const* d_in, const int* in_sizes, int n_in,
                              void* d_out, int out_size, void* d_ws, size_t ws_size,
                              hipStream_t stream) {
    (void)in_sizes; (void)n_in; (void)out_size; (void)ws_size;
    const float* x    = (const float*)d_in[0];
    const float* ctrl = (const float*)d_in[1];
    const float* f1   = (const float*)d_in[2];
    const float* bias = (const float*)d_in[3];
    const float* f2   = (const float*)d_in[4];
    float* out = (float*)d_out;

    char* ws = (char*)d_ws;
    int*    idx = (int*)ws;                         // 128 KB
    ushort* Hb  = (ushort*)(ws + 131072);           // 2 MB
    ushort* f1T = (ushort*)(ws + 2228224);          // 8 MB
    ushort* f2T = (ushort*)(ws + 10616832);         // 8 MB
    ushort* xb  = (ushort*)(ws + 19005440);         // 16 MB
    ushort* cFh = (ushort*)(ws + 35782656);         // 256 KB
    ushort* cFl = (ushort*)(ws + 36044800);         // 256 KB (end ~34.6 MB)

    k_prep<<<392, 256, 0, stream>>>(f1, f2, x, ctrl, f1T, f2T, xb, cFh, cFl);

    const size_t lds1 = 65536;
    hipFuncSetAttribute((const void*)k_logits_mfma,
                        hipFuncAttributeMaxDynamicSharedMemorySize, (int)lds1);
    k_logits_mfma<<<NGROUP, 256, lds1, stream>>>(x, cFh, cFl, idx);

    const size_t lds2 = 65536;
    hipFuncSetAttribute((const void*)k_h_mfma,
                        hipFuncAttributeMaxDynamicSharedMemorySize, (int)lds2);
    k_h_mfma<<<NSLOT * 2, 256, lds2, stream>>>(xb, f1T, bias, idx, Hb);

    const size_t lds3 = 131328 + 20480 + 8192;      // 160000
    hipFuncSetAttribute((const void*)k_out_mfma,
                        hipFuncAttributeMaxDynamicSharedMemorySize, (int)lds3);
    k_out_mfma<<<256, 256, lds3, stream>>>(Hb, f2T, idx, out);
}

// Round 5
// 99.978 us; speedup vs baseline: 11.8182x; 1.2311x over previous
//
#include <hip/hip_runtime.h>
#include <hip/hip_bf16.h>

#define NGROUP 256   // B * (SEQ/TG)
#define NSLOT  128   // experts * sets
#define TG     32    // tokens per group
#define DM     1024  // model dim
#define FF     32    // expert size

#define LSCALE     4096.0f
#define INV_LSCALE (1.0f / 4096.0f)

typedef unsigned int  uint;
typedef unsigned short ushort;
typedef __attribute__((ext_vector_type(4))) float f32x4;
typedef __attribute__((ext_vector_type(8))) short bf16x8;
typedef __attribute__((ext_vector_type(8))) _Float16 f16x8;

__device__ __forceinline__ ushort f2bf(float f) {
    uint u = __float_as_uint(f);
    u += 0x7FFFu + ((u >> 16) & 1u);   // RNE
    return (ushort)(u >> 16);
}
__device__ __forceinline__ uint pk2(float a, float b) {
    return (uint)f2bf(a) | ((uint)f2bf(b) << 16);
}

// ---------------------------------------------------------------------------
// K0: prep.
//  blocks 0..127   : f1[d][es][f] -> f1T[es][f][d]  bf16 (MFMA-B layout)
//  blocks 128..255 : f2[es][f][d] -> f2T[es][d][f]  bf16 (MFMA-A layout)
//  blocks 256..263 : ctrl -> cFh/cFl fp16 split, MFMA-fragment order
// (x -> bf16 cast is fused into k_logits_mfma, which reads x exactly once.)
// ---------------------------------------------------------------------------
__global__ __launch_bounds__(256) void k_prep(
    const float* __restrict__ f1, const float* __restrict__ f2,
    const float* __restrict__ ctrl,
    ushort* __restrict__ f1T, ushort* __restrict__ f2T,
    ushort* __restrict__ cFh, ushort* __restrict__ cFl)
{
    __shared__ float Ltr[64 * 33];
    const int t = threadIdx.x;
    if (blockIdx.x < 128) {
        const int es = blockIdx.x;
        for (int d0 = 0; d0 < DM; d0 += 64) {
            const int dd = t >> 2, f0 = (t & 3) * 8;
            const float* src = f1 + (size_t)(d0 + dd) * 4096 + es * FF + f0;
            float4 a = *(const float4*)src;
            float4 b = *(const float4*)(src + 4);
            __syncthreads();
            float* Lp = &Ltr[dd * 33 + f0];
            Lp[0] = a.x; Lp[1] = a.y; Lp[2] = a.z; Lp[3] = a.w;
            Lp[4] = b.x; Lp[5] = b.y; Lp[6] = b.z; Lp[7] = b.w;
            __syncthreads();
            const int f = t >> 3, dd8 = (t & 7) * 8;
            uint4 o;
            o.x = pk2(Ltr[(dd8 + 0) * 33 + f], Ltr[(dd8 + 1) * 33 + f]);
            o.y = pk2(Ltr[(dd8 + 2) * 33 + f], Ltr[(dd8 + 3) * 33 + f]);
            o.z = pk2(Ltr[(dd8 + 4) * 33 + f], Ltr[(dd8 + 5) * 33 + f]);
            o.w = pk2(Ltr[(dd8 + 6) * 33 + f], Ltr[(dd8 + 7) * 33 + f]);
            *(uint4*)(f1T + (size_t)es * (FF * DM) + f * DM + d0 + dd8) = o;
        }
    } else if (blockIdx.x < 256) {
        const int es = blockIdx.x - 128;
        for (int d0 = 0; d0 < DM; d0 += 64) {
            const int f = t >> 3, ds = (t & 7) * 8;
            const float* src = f2 + (size_t)es * (FF * DM) + f * DM + d0 + ds;
            float4 a = *(const float4*)src;
            float4 b = *(const float4*)(src + 4);
            __syncthreads();
            Ltr[(ds + 0) * 33 + f] = a.x; Ltr[(ds + 1) * 33 + f] = a.y;
            Ltr[(ds + 2) * 33 + f] = a.z; Ltr[(ds + 3) * 33 + f] = a.w;
            Ltr[(ds + 4) * 33 + f] = b.x; Ltr[(ds + 5) * 33 + f] = b.y;
            Ltr[(ds + 6) * 33 + f] = b.z; Ltr[(ds + 7) * 33 + f] = b.w;
            __syncthreads();
            const int dd = t >> 2, f0 = (t & 3) * 8;
            uint4 o;
            o.x = pk2(Ltr[dd * 33 + f0 + 0], Ltr[dd * 33 + f0 + 1]);
            o.y = pk2(Ltr[dd * 33 + f0 + 2], Ltr[dd * 33 + f0 + 3]);
            o.z = pk2(Ltr[dd * 33 + f0 + 4], Ltr[dd * 33 + f0 + 5]);
            o.w = pk2(Ltr[dd * 33 + f0 + 6], Ltr[dd * 33 + f0 + 7]);
            *(uint4*)(f2T + (size_t)es * (FF * DM) + (d0 + dd) * FF + f0) = o;
        }
    } else {
        // ctrl -> fp16 hi/lo in fragment order:
        // octet o: lane=o&63, ks=(o>>6)&31, nt=o>>11;
        // element j: k = ks*32 + (lane>>4)*8 + j, n = nt*16 + (lane&15)
        const int base_o = ((blockIdx.x - 256) * 256 + t) * 8;
#pragma unroll
        for (int q = 0; q < 8; ++q) {
            const int o = base_o + q;
            const int lane = o & 63, ks = (o >> 6) & 31, nt = o >> 11;
            const int k = ks * 32 + ((lane >> 4) << 3);
            const int n = nt * 16 + (lane & 15);
            union { f16x8 v; _Float16 e[8]; } H, L;
#pragma unroll
            for (int j = 0; j < 8; ++j) {
                const float c = ctrl[(size_t)(k + j) * NSLOT + n];
                const _Float16 h = (_Float16)c;
                H.e[j] = h;
                L.e[j] = (_Float16)((c - (float)h) * LSCALE);
            }
            *(f16x8*)(cFh + (size_t)o * 8) = H.v;
            *(f16x8*)(cFl + (size_t)o * 8) = L.v;
        }
    }
}

// ---------------------------------------------------------------------------
// K1: controller logits + tie-broken argmax via split-fp16 MFMA, and
// (fused) x -> xb bf16 cast (each x element is read exactly once here).
// grid = 256 groups, 256 thr (4 waves). Wave w owns K-chunk [w*256,(w+1)*256).
// L = sum xh*ch + (sum xh*cl + sum xl*ch)/4096, fp32 MFMA accumulators.
// LDS: Lp[4][32][128] fp32 partials -> tree reduce -> argmax (proven code).
// ---------------------------------------------------------------------------
__global__ __launch_bounds__(256) void k_logits_mfma(
    const float* __restrict__ x, const ushort* __restrict__ cFh,
    const ushort* __restrict__ cFl, int* __restrict__ idx,
    ushort* __restrict__ xb)
{
    extern __shared__ float Lp[];   // [4][32][128] = 64 KB
    const int g = blockIdx.x;
    const int w = threadIdx.x >> 6;
    const int lane = threadIdx.x & 63;
    const int lrow = lane & 15;
    const int lk8 = (lane >> 4) * 8;

    const size_t xoff0 = ((size_t)g * TG + lrow) * DM + w * 256 + lk8;
    const float* xr0 = x + xoff0;
    const float* xr1 = xr0 + 16 * DM;

    f32x4 ahh[2][8], ax[2][8];
#pragma unroll
    for (int mt = 0; mt < 2; ++mt)
#pragma unroll
        for (int nt = 0; nt < 8; ++nt) {
            ahh[mt][nt] = (f32x4){0.f, 0.f, 0.f, 0.f};
            ax[mt][nt]  = (f32x4){0.f, 0.f, 0.f, 0.f};
        }

    for (int ks = 0; ks < 8; ++ks) {
        f16x8 Ah[2], Al[2];
#pragma unroll
        for (int mt = 0; mt < 2; ++mt) {
            const float* p = (mt ? xr1 : xr0) + ks * 32;
            float xe[8];
            *(float4*)&xe[0] = *(const float4*)p;
            *(float4*)&xe[4] = *(const float4*)(p + 4);
            union { f16x8 v; _Float16 e[8]; } H, L;
#pragma unroll
            for (int j = 0; j < 8; ++j) {
                const _Float16 h = (_Float16)xe[j];
                H.e[j] = h;
                L.e[j] = (_Float16)((xe[j] - (float)h) * LSCALE);
            }
            Ah[mt] = H.v; Al[mt] = L.v;
            // fused bf16 cast (identical RNE values to the old k_prep cast)
            uint4 o;
            o.x = pk2(xe[0], xe[1]); o.y = pk2(xe[2], xe[3]);
            o.z = pk2(xe[4], xe[5]); o.w = pk2(xe[6], xe[7]);
            *(uint4*)(xb + xoff0 + (size_t)mt * 16 * DM + ks * 32) = o;
        }
#pragma unroll
        for (int nt = 0; nt < 8; ++nt) {
            const size_t fo = (((size_t)nt * 32 + (w * 8 + ks)) * 64 + lane) * 8;
            const f16x8 Bh = *(const f16x8*)(cFh + fo);
            const f16x8 Bl = *(const f16x8*)(cFl + fo);
#pragma unroll
            for (int mt = 0; mt < 2; ++mt) {
                ahh[mt][nt] = __builtin_amdgcn_mfma_f32_16x16x32_f16(Ah[mt], Bh, ahh[mt][nt], 0, 0, 0);
                ax[mt][nt]  = __builtin_amdgcn_mfma_f32_16x16x32_f16(Al[mt], Bh, ax[mt][nt], 0, 0, 0);
                ax[mt][nt]  = __builtin_amdgcn_mfma_f32_16x16x32_f16(Ah[mt], Bl, ax[mt][nt], 0, 0, 0);
            }
        }
    }

    // write per-wave partial logits: row = mt*16 + (lane>>4)*4 + r, col = nt*16 + lrow
#pragma unroll
    for (int mt = 0; mt < 2; ++mt)
#pragma unroll
        for (int nt = 0; nt < 8; ++nt)
#pragma unroll
            for (int r = 0; r < 4; ++r) {
                const int trow = mt * 16 + (lane >> 4) * 4 + r;
                const int n = nt * 16 + lrow;
                Lp[(w * TG + trow) * NSLOT + n] =
                    ahh[mt][nt][r] + ax[mt][nt][r] * INV_LSCALE;
            }
    __syncthreads();

    for (int i = threadIdx.x * 4; i < TG * NSLOT; i += 256 * 4) {
        f32x4 s0 = *(const f32x4*)&Lp[i];
        f32x4 s1 = *(const f32x4*)&Lp[4096 + i];
        f32x4 s2 = *(const f32x4*)&Lp[8192 + i];
        f32x4 s3 = *(const f32x4*)&Lp[12288 + i];
        *(f32x4*)&Lp[i] = (s0 + s1) + (s2 + s3);
    }
    __syncthreads();

    if (threadIdx.x < NSLOT) {
        const int n = threadIdx.x;
        float best = -1e30f;
        int bi = 0;
#pragma unroll
        for (int t = 0; t < TG; ++t) {
            const float v = Lp[t * NSLOT + n] + (float)t * (1e-6f / 31.0f);
            if (v >= best) { best = v; bi = t; }   // later token wins ties
        }
        idx[g * NSLOT + n] = bi;
    }
}

// ---------------------------------------------------------------------------
// K2: H = relu(x_gathered @ f1 + bias) via MFMA 16x16x32 bf16. UNCHANGED.
// ---------------------------------------------------------------------------
__global__ __launch_bounds__(256) void k_h_mfma(
    const ushort* __restrict__ xb, const ushort* __restrict__ f1T,
    const float* __restrict__ bias, const int* __restrict__ idx,
    ushort* __restrict__ Hb)
{
    extern __shared__ char smK2[];

    const int es = blockIdx.x >> 1;
    const int gh = blockIdx.x & 1;

    {
        const ushort* src = f1T + (size_t)es * (FF * DM);
        for (int e = threadIdx.x * 8; e < FF * DM; e += 256 * 8) {
            uint4 v = *(const uint4*)(src + e);
            const int f = e >> 10, k = e & 1023;
            const int byt = f * 2048 + ((k * 2) ^ ((f & 7) << 4));
            *(uint4*)(smK2 + byt) = v;
        }
    }
    __syncthreads();

    const int w = threadIdx.x >> 6;
    const int lane = threadIdx.x & 63;
    const int lrow = lane & 15;
    const int lk8 = (lane >> 4) * 8;

    const ushort* abase[2];
#pragma unroll
    for (int mt = 0; mt < 2; ++mt) {
        const int g = gh * 128 + w * 32 + mt * 16 + lrow;
        const int tok = idx[g * NSLOT + es];
        abase[mt] = xb + ((size_t)g * TG + tok) * DM + lk8;
    }

    f32x4 acc[2][2];
#pragma unroll
    for (int mt = 0; mt < 2; ++mt)
#pragma unroll
        for (int nt = 0; nt < 2; ++nt) acc[mt][nt] = (f32x4){0.f, 0.f, 0.f, 0.f};

#pragma unroll 2
    for (int k0 = 0; k0 < DM; k0 += 32) {
        bf16x8 bfr[2];
#pragma unroll
        for (int nt = 0; nt < 2; ++nt) {
            const int f = nt * 16 + lrow;
            const int k = k0 + lk8;
            bfr[nt] = *(const bf16x8*)(smK2 + f * 2048 + ((k * 2) ^ ((f & 7) << 4)));
        }
#pragma unroll
        for (int mt = 0; mt < 2; ++mt) {
            const bf16x8 A = *(const bf16x8*)(abase[mt] + k0);
#pragma unroll
            for (int nt = 0; nt < 2; ++nt)
                acc[mt][nt] = __builtin_amdgcn_mfma_f32_16x16x32_bf16(
                    A, bfr[nt], acc[mt][nt], 0, 0, 0);
        }
    }

#pragma unroll
    for (int nt = 0; nt < 2; ++nt) {
        const int f = nt * 16 + lrow;
        const float bv = bias[es * FF + f];
#pragma unroll
        for (int mt = 0; mt < 2; ++mt) {
#pragma unroll
            for (int r = 0; r < 4; ++r) {
                const int g = gh * 128 + w * 32 + mt * 16 + (lane >> 4) * 4 + r;
                const float hv = fmaxf(acc[mt][nt][r] + bv, 0.0f);
                Hb[(size_t)g * (NSLOT * FF) + es * FF + f] = f2bf(hv);
            }
        }
    }
}

// ---------------------------------------------------------------------------
// K3 (rewritten): out accumulation via per-es MFMA + LDS scatter-accumulate.
// NO LDS staging of f2T (it's L2-resident: read A directly from global,
// perfectly coalesced 16 B/lane), NO barriers in the es loop (the OL RMW is
// race-free by construction: waves own disjoint dloc ranges, lanes disjoint
// f32x4s, per-wave LDS ops are in-order). 2 barriers total instead of 128.
// ---------------------------------------------------------------------------
__global__ __launch_bounds__(256) void k_out_mfma(
    const ushort* __restrict__ Hb, const ushort* __restrict__ f2T,
    const int* __restrict__ idx, float* __restrict__ out)
{
    extern __shared__ char smK3[];
    float* OL   = (float*)smK3;              // [16][2052] = 131328 B
    int* idxs_t = (int*)(smK3 + 131328);     // [128][16]  = 8192 B

    const int G0 = (blockIdx.x >> 4) * 16;
    const int D0 = (blockIdx.x & 15) * 64;
    const int tid = threadIdx.x;
    const int w = tid >> 6;
    const int lane = tid & 63;
    const int gl = lane & 15;
    const int lk8 = (lane >> 4) * 8;

    for (int i = tid * 4; i < 32768; i += 1024)
        *(f32x4*)&OL[i] = (f32x4){0.f, 0.f, 0.f, 0.f};
    if (tid < 16) *(f32x4*)&OL[32768 + tid * 4] = (f32x4){0.f, 0.f, 0.f, 0.f};
    for (int i = tid; i < NSLOT * 16; i += 256)
        idxs_t[i] = idx[(G0 + (i & 15)) * NSLOT + (i >> 4)];
    __syncthreads();

    // A: f2T[es][d][f], d = D0 + w*16 + gl, f = lk8..lk8+7 (wave reads a
    //    contiguous 1 KB slab per es). B: Hb[G0+gl][es][lk8..+7].
    const ushort* ap = f2T + (size_t)(D0 + w * 16 + gl) * FF + lk8;
    const ushort* bp = Hb + (size_t)(G0 + gl) * (NSLOT * FF) + lk8;
    const int dloc = w * 16 + (lane >> 4) * 4;
    float* olbase = &OL[gl * 2052 + dloc];

#pragma unroll 4
    for (int es = 0; es < NSLOT; ++es) {
        const bf16x8 afr = *(const bf16x8*)(ap + (size_t)es * (FF * DM));
        const bf16x8 bfr = *(const bf16x8*)(bp + es * FF);
        const f32x4 d = __builtin_amdgcn_mfma_f32_16x16x32_bf16(
            afr, bfr, (f32x4){0.f, 0.f, 0.f, 0.f}, 0, 0, 0);
        const int t = idxs_t[es * 16 + gl];
        float* olp = olbase + t * 64;
        *(f32x4*)olp = *(const f32x4*)olp + d;
    }
    __syncthreads();

    // dense write-out: every (g, t, d) exactly once
    for (int it = 0; it < 32; ++it) {
        const int flat = tid * 4 + it * 1024;
        const int gli = flat >> 11, rem = flat & 2047;
        const int t = rem >> 6, d = rem & 63;
        const f32x4 v = *(const f32x4*)&OL[gli * 2052 + rem];
        *(f32x4*)&out[((size_t)(G0 + gli) * TG + t) * DM + D0 + d] = v;
    }
}

// ---------------------------------------------------------------------------
extern "C" void kernel_launch(void* const* d_in, const int* in_sizes, int n_in,
                              void* d_out, int out_size, void* d_ws, size_t ws_size,
                              hipStream_t stream) {
    (void)in_sizes; (void)n_in; (void)out_size; (void)ws_size;
    const float* x    = (const float*)d_in[0];
    const float* ctrl = (const float*)d_in[1];
    const float* f1   = (const float*)d_in[2];
    const float* bias = (const float*)d_in[3];
    const float* f2   = (const float*)d_in[4];
    float* out = (float*)d_out;

    char* ws = (char*)d_ws;
    int*    idx = (int*)ws;                         // 128 KB
    ushort* Hb  = (ushort*)(ws + 131072);           // 2 MB
    ushort* f1T = (ushort*)(ws + 2228224);          // 8 MB
    ushort* f2T = (ushort*)(ws + 10616832);         // 8 MB
    ushort* xb  = (ushort*)(ws + 19005440);         // 16 MB
    ushort* cFh = (ushort*)(ws + 35782656);         // 256 KB
    ushort* cFl = (ushort*)(ws + 36044800);         // 256 KB

    k_prep<<<264, 256, 0, stream>>>(f1, f2, ctrl, f1T, f2T, cFh, cFl);

    const size_t lds1 = 65536;
    hipFuncSetAttribute((const void*)k_logits_mfma,
                        hipFuncAttributeMaxDynamicSharedMemorySize, (int)lds1);
    k_logits_mfma<<<NGROUP, 256, lds1, stream>>>(x, cFh, cFl, idx, xb);

    const size_t lds2 = 65536;
    hipFuncSetAttribute((const void*)k_h_mfma,
                        hipFuncAttributeMaxDynamicSharedMemorySize, (int)lds2);
    k_h_mfma<<<NSLOT * 2, 256, lds2, stream>>>(xb, f1T, bias, idx, Hb);

    const size_t lds3 = 131328 + 8192;              // 139520
    hipFuncSetAttribute((const void*)k_out_mfma,
                        hipFuncAttributeMaxDynamicSharedMemorySize, (int)lds3);
    k_out_mfma<<<256, 256, lds3, stream>>>(Hb, f2T, idx, out);
}